// Round 14
// baseline (266.909 us; speedup 1.0000x reference)
//
#include <hip/hip_runtime.h>
#include <hip/hip_bf16.h>

typedef __attribute__((ext_vector_type(4))) float f32x4;

#define EPB 4096      // edges per partition block
#define NBKT 196      // ceil(100000/512) buckets of 512 nodes
#define BCAP 10240    // arena capacity per bucket (mean 8192, +22 sigma)

// =============== Phase B: partition edges into per-bucket arenas ================
// All per-edge work uses LDS atomics; global atomics only 1 per (block,bucket).
__global__ __launch_bounds__(256)
void partition_kernel(const int* __restrict__ ei, int E,
                      int* __restrict__ bktCur, int* __restrict__ arena) {
    __shared__ int sHist[256];       // 196 used (padded to 256)
    __shared__ int sScan[256];
    __shared__ int sAdj[256];
    __shared__ int2 sEdges[EPB];     // 32 KB staging
    const int t = threadIdx.x;
    const int e0 = blockIdx.x * EPB;
    const int ecnt = min(EPB, E - e0);
    const int* src = ei;
    const int* dst = ei + E;

    sHist[t] = 0;
    __syncthreads();
    for (int k = t; k < ecnt; k += 256) {        // stage + histogram
        const int s = src[e0 + k], d = dst[e0 + k];
        sEdges[k] = make_int2(s, d);
        atomicAdd(&sHist[d >> 9], 1);
    }
    __syncthreads();
    const int v = sHist[t];                      // block-exclusive scan (Hillis-Steele)
    sScan[t] = v;
    __syncthreads();
    #pragma unroll
    for (int off = 1; off < 256; off <<= 1) {
        const int y = (t >= off) ? sScan[t - off] : 0;
        __syncthreads();
        sScan[t] += y;
        __syncthreads();
    }
    const int excl = sScan[t] - v;
    if (t < NBKT && v > 0) {                     // reserve arena space (1 atomic/bucket)
        const int g = atomicAdd(&bktCur[t], v);
        sAdj[t] = t * BCAP + g - excl;           // sorted pos p -> arena slot sAdj[b]+p
    }
    sHist[t] = excl;                             // reuse as local placement cursor
    __syncthreads();
    for (int k = t; k < ecnt; k += 256) {        // place packed (src<<9 | d&511)
        const int2 e = sEdges[k];
        const int b = e.y >> 9;
        const int p = atomicAdd(&sHist[b], 1);
        arena[sAdj[b] + p] = (e.x << 9) | (e.y & 511);
    }
}

// =============== Phase C: per-bucket CSR build + meta + dis + g0 = dis*x =========
__global__ __launch_bounds__(512)
void bucket_csr_kernel(const int* __restrict__ arena, const int* __restrict__ bktCur,
                       int* __restrict__ csr_src, int2* __restrict__ meta,
                       float* __restrict__ dis, const float* __restrict__ x,
                       float* __restrict__ g0, int n) {
    __shared__ int sHist[512];
    __shared__ int sScan[512];
    const int t = threadIdx.x;
    const int b = blockIdx.x;
    const int base = b * BCAP;
    const int cnt_b = min(bktCur[b], BCAP);

    sHist[t] = 0;
    __syncthreads();
    for (int e = t; e < cnt_b; e += 512)
        atomicAdd(&sHist[arena[base + e] & 511], 1);
    __syncthreads();
    const int v = sHist[t];
    sScan[t] = v;
    __syncthreads();
    #pragma unroll
    for (int off = 1; off < 512; off <<= 1) {
        const int y = (t >= off) ? sScan[t - off] : 0;
        __syncthreads();
        sScan[t] += y;
        __syncthreads();
    }
    const int excl = sScan[t] - v;
    const int node = b * 512 + t;
    if (node < n) {
        meta[node] = make_int2(base + excl, v);
        const float d = (float)(1.0 / sqrt((double)(v + 1)));
        dis[node] = d;
        float2 xv = *(const float2*)(x + 2 * (size_t)node);
        xv.x *= d; xv.y *= d;
        *(float2*)(g0 + 2 * (size_t)node) = xv;
    }
    sHist[t] = excl;                             // local cursor
    __syncthreads();
    for (int e = t; e < cnt_b; e += 512) {
        const int pv = arena[base + e];
        const int p = atomicAdd(&sHist[pv & 511], 1);
        csr_src[base + p] = pv >> 9;             // random 4B within 40KB window: L2-hot
    }
}

// =============== Layer 1: [N,2] -> g1[N,16]. Wave per node. ======================
// agg = dis[node]*(sum g0[src] + g0[node]); out g1 = dis[node]*relu(agg@W1+b1).
__global__ __launch_bounds__(256, 4)
void gcn_l1(const float* __restrict__ g0, const int2* __restrict__ meta,
            const int* __restrict__ csr_src, const float* __restrict__ dis,
            const float* __restrict__ W, const float* __restrict__ B,
            float* __restrict__ g1, int n, int nwaves) {
    const int lane = threadIdx.x & 63;
    const int wid = blockIdx.x * (blockDim.x >> 6) + (threadIdx.x >> 6);
    const int chunk = (n + nwaves - 1) / nwaves;
    const int n0 = wid * chunk, n1 = min(n0 + chunk, n);
    const int o = lane & 15;
    const float w0 = W[o], w1 = W[16 + o], bo = B[o];
    for (int node = n0; node < n1; ++node) {
        const int2 mt = meta[node];
        const int start = mt.x, m = mt.y;
        float a0 = 0.f, a1 = 0.f;
        for (int j = lane; j < m; j += 64) {
            const int s2 = csr_src[start + j];
            const float2 hv = *(const float2*)(g0 + 2 * (size_t)s2);
            a0 += hv.x;
            a1 += hv.y;
        }
        #pragma unroll
        for (int off = 32; off >= 1; off >>= 1) {
            a0 += __shfl_xor(a0, off);
            a1 += __shfl_xor(a1, off);
        }
        const float d0 = dis[node];
        const float2 hs = *(const float2*)(g0 + 2 * (size_t)node);
        a0 = (a0 + hs.x) * d0;
        a1 = (a1 + hs.y) * d0;
        if (lane < 16) {
            const float v = fmaxf(fmaf(a0, w0, fmaf(a1, w1, bo)), 0.f);
            g1[(size_t)node * 16 + o] = d0 * v;
        }
    }
}

// =============== AGG: agg[node] = dis[node]*(sum g[src] + g[node]). ==============
// One wave per node. R13 lesson: 4-deep cluster left only ~22 reqs in flight/SIMD;
// UNROLL=32/EPW puts a whole 32-slot round (covers mean degree 17) in ONE
// latency round-trip. Asm cluster defeats compiler re-serialization (R3/R4).
template <int C_IN>
__global__ __launch_bounds__(256, 6)
void agg_kernel(const float* __restrict__ g_in, const int2* __restrict__ meta,
                const int* __restrict__ csr_src, const float* __restrict__ dis,
                float* __restrict__ agg, int n) {
    constexpr int LPR = C_IN / 4;                      // 4, 8, 16
    constexpr int EPW = 64 / LPR;                      // 16, 8, 4
    constexpr int LOGL = (LPR == 4) ? 2 : (LPR == 8) ? 3 : 4;
    constexpr int UNROLL = 32 / EPW;                   // 2, 4, 8 -> 32-slot stride

    const int lane = threadIdx.x & 63;
    const int node = blockIdx.x * 4 + (threadIdx.x >> 6);
    if (node >= n) return;

    const int2 mt = meta[node];
    const int start = mt.x, m = mt.y;
    const int cb = (lane & (LPR - 1)) * 4;
    const int sub = lane >> LOGL;

    float ax = 0.f, ay = 0.f, az = 0.f, aw = 0.f;
    for (int j = sub; j < m; j += UNROLL * EPW) {
        int ss[UNROLL];
        float mm[UNROLL];
        #pragma unroll
        for (int u = 0; u < UNROLL; ++u) {
            const int jj = j + u * EPW;
            const bool ok = jj < m;
            ss[u] = csr_src[start + (ok ? jj : 0)];    // dummy -> edge 0 (L1-hot)
            mm[u] = ok ? 1.f : 0.f;
        }
        f32x4 hv[UNROLL];
        const float* ap[UNROLL];
        #pragma unroll
        for (int u = 0; u < UNROLL; ++u) ap[u] = g_in + (size_t)ss[u] * C_IN + cb;
        #pragma unroll
        for (int u = 0; u < UNROLL; ++u)
            asm volatile("global_load_dwordx4 %0, %1, off"
                         : "=v"(hv[u]) : "v"(ap[u]) : "memory");
        asm volatile("s_waitcnt vmcnt(0)" ::: "memory");
        __builtin_amdgcn_sched_barrier(0);             // rule #18
        #pragma unroll
        for (int u = 0; u < UNROLL; ++u) {
            ax = fmaf(mm[u], hv[u].x, ax); ay = fmaf(mm[u], hv[u].y, ay);
            az = fmaf(mm[u], hv[u].z, az); aw = fmaf(mm[u], hv[u].w, aw);
        }
    }
    #pragma unroll
    for (int off = 32; off >= LPR; off >>= 1) {
        ax += __shfl_xor(ax, off); ay += __shfl_xor(ay, off);
        az += __shfl_xor(az, off); aw += __shfl_xor(aw, off);
    }
    if (lane < LPR) {
        const f32x4 hs = *(const f32x4*)(g_in + (size_t)node * C_IN + cb);
        const float d0 = dis[node];
        ax = (ax + hs.x) * d0; ay = (ay + hs.y) * d0;
        az = (az + hs.z) * d0; aw = (aw + hs.w) * d0;
        f32x4 t; t.x = ax; t.y = ay; t.z = az; t.w = aw;
        *(f32x4*)&agg[(size_t)node * C_IN + cb] = t;
    }
}

// =============== GEMM: g_out = dis*relu(agg @ W + B)  (or FPOOL epilogue). ========
template <int C_IN, int C_OUT, bool FPOOL>
__global__ __launch_bounds__(256, 3)
void gemm_kernel(const float* __restrict__ agg, const float* __restrict__ W,
                 const float* __restrict__ Bias, const float* __restrict__ dis,
                 float* __restrict__ g_out, const int* __restrict__ batchv,
                 float* __restrict__ pooled, int n) {
    constexpr int QW = C_OUT / 16;                 // out-quads per wave: 2,4,8
    constexpr int RPT = QW;                        // rows per thread: 2,4,8
    constexpr int LOGQ = (QW == 8) ? 3 : (QW == 4) ? 2 : 1;
    constexpr int CH = C_IN / 4;                   // f32x4 chunks per agg row
    constexpr int SA = 68;                         // At row stride
    constexpr int SP = 133;                        // sP row stride

    constexpr int W_BYTES = C_IN * C_OUT * 4 + C_OUT * 4;
    constexpr int P_BYTES = FPOOL ? (64 * SP * 4) : 0;
    constexpr int R1 = ((W_BYTES > P_BYTES ? W_BYTES : P_BYTES) + 15) & ~15;
    constexpr int AT_BYTES = C_IN * SA * 4;
    __shared__ char smem[R1 + AT_BYTES];
    __shared__ int sGb[64];
    __shared__ float sDis[64];

    float* sW = (float*)smem;
    float* sB = sW + C_IN * C_OUT;
    float* sP = (float*)smem;                      // overlays sW after k-loop (FPOOL)
    float* sAt = (float*)(smem + R1);

    const int tid = threadIdx.x;
    const int base = blockIdx.x * 64;

    for (int i = tid; i < C_IN * C_OUT / 4; i += 256)
        ((f32x4*)sW)[i] = ((const f32x4*)W)[i];
    if (tid < C_OUT) sB[tid] = Bias[tid];
    {   // stage agg transposed: At[k][row] (zero past n)
        constexpr int RPP = 256 / CH;
        const int r = tid / CH, c0 = tid % CH;
        #pragma unroll
        for (int p = 0; p < 64 / RPP; ++p) {
            const int rr = p * RPP + r;
            const int node = base + rr;
            f32x4 v = {0.f, 0.f, 0.f, 0.f};
            if (node < n) v = *(const f32x4*)&agg[(size_t)node * C_IN + c0 * 4];
            sAt[(c0 * 4 + 0) * SA + rr] = v.x;
            sAt[(c0 * 4 + 1) * SA + rr] = v.y;
            sAt[(c0 * 4 + 2) * SA + rr] = v.z;
            sAt[(c0 * 4 + 3) * SA + rr] = v.w;
        }
    }
    if (FPOOL && tid < 64) sGb[tid] = (base + tid < n) ? batchv[base + tid] : -1;
    if (!FPOOL && tid < 64) sDis[tid] = (base + tid < n) ? dis[base + tid] : 0.f;
    __syncthreads();

    const int w = tid >> 6, l = tid & 63;
    const int j = l & (QW - 1);
    const int rg = l >> LOGQ;
    const int ob = w * (C_OUT / 4) + j * 4;

    f32x4 acc[RPT];
    {
        const f32x4 bv = *(const f32x4*)&sB[ob];
        #pragma unroll
        for (int r = 0; r < RPT; ++r) acc[r] = bv;
    }

    #pragma unroll 4
    for (int k = 0; k < C_IN; ++k) {
        const f32x4 wv = ((const f32x4*)sW)[k * (C_OUT / 4) + (ob >> 2)];
        float av[RPT];
        if constexpr (RPT == 8) {
            const f32x4 a0 = *(const f32x4*)&sAt[k * SA + rg * 8];
            const f32x4 a1 = *(const f32x4*)&sAt[k * SA + rg * 8 + 4];
            av[0] = a0.x; av[1] = a0.y; av[2] = a0.z; av[3] = a0.w;
            av[4] = a1.x; av[5] = a1.y; av[6] = a1.z; av[7] = a1.w;
        } else if constexpr (RPT == 4) {
            const f32x4 a0 = *(const f32x4*)&sAt[k * SA + rg * 4];
            av[0] = a0.x; av[1] = a0.y; av[2] = a0.z; av[3] = a0.w;
        } else {
            const float2 a0 = *(const float2*)&sAt[k * SA + rg * 2];
            av[0] = a0.x; av[1] = a0.y;
        }
        #pragma unroll
        for (int r = 0; r < RPT; ++r) {
            acc[r].x = fmaf(av[r], wv.x, acc[r].x);
            acc[r].y = fmaf(av[r], wv.y, acc[r].y);
            acc[r].z = fmaf(av[r], wv.z, acc[r].z);
            acc[r].w = fmaf(av[r], wv.w, acc[r].w);
        }
    }

    if constexpr (!FPOOL) {
        #pragma unroll
        for (int r = 0; r < RPT; ++r) {
            const int row = rg * RPT + r;
            const int node = base + row;
            if (node < n) {
                const float sd = sDis[row];
                f32x4 o;
                o.x = sd * fmaxf(acc[r].x, 0.f); o.y = sd * fmaxf(acc[r].y, 0.f);
                o.z = sd * fmaxf(acc[r].z, 0.f); o.w = sd * fmaxf(acc[r].w, 0.f);
                *(f32x4*)&g_out[(size_t)node * C_OUT + ob] = o;
            }
        }
    } else {
        __syncthreads();                           // k-loop reads of sW done (overlay!)
        #pragma unroll
        for (int r = 0; r < RPT; ++r) {
            const int row = rg * RPT + r;
            sP[row * SP + ob + 0] = fmaxf(acc[r].x, 0.f);
            sP[row * SP + ob + 1] = fmaxf(acc[r].y, 0.f);
            sP[row * SP + ob + 2] = fmaxf(acc[r].z, 0.f);
            sP[row * SP + ob + 3] = fmaxf(acc[r].w, 0.f);
        }
        __syncthreads();
        if (tid < 128) {                           // one thread per out column
            const int c = tid;
            int curg = -1; float run = 0.f;
            for (int r = 0; r < 64; ++r) {
                const int gb = sGb[r];
                if (gb < 0) continue;
                const float v = sP[r * SP + c];
                if (gb != curg) {
                    if (curg >= 0)
                        atomicMax((int*)&pooled[(size_t)curg * 128 + c], __float_as_int(run));
                    curg = gb; run = v;
                } else {
                    run = fmaxf(run, v);
                }
            }
            if (curg >= 0)
                atomicMax((int*)&pooled[(size_t)curg * 128 + c], __float_as_int(run));
        }
    }
}

// ---------------- MLP head: relu(pooled @ W5 + b5) @ W6 + b6 ----------------
__global__ void mlp_kernel(const float* __restrict__ pooled,
                           const float* __restrict__ W5, const float* __restrict__ b5,
                           const float* __restrict__ W6, const float* __restrict__ b6,
                           float* __restrict__ out) {
    const int g = blockIdx.x;
    const int t = threadIdx.x;  // 64 threads
    __shared__ float row[128];
    __shared__ float hid[64];
    row[t] = pooled[g * 128 + t];
    row[64 + t] = pooled[g * 128 + 64 + t];
    __syncthreads();
    float v = b5[t];
    #pragma unroll 8
    for (int c = 0; c < 128; ++c) v = fmaf(row[c], W5[c * 64 + t], v);
    hid[t] = fmaxf(v, 0.f);
    __syncthreads();
    if (t < 10) {
        float o = b6[t];
        #pragma unroll 8
        for (int c = 0; c < 64; ++c) o = fmaf(hid[c], W6[c * 10 + t], o);
        out[g * 10 + t] = o;
    }
}

extern "C" void kernel_launch(void* const* d_in, const int* in_sizes, int n_in,
                              void* d_out, int out_size, void* d_ws, size_t ws_size,
                              hipStream_t stream) {
    const float* x     = (const float*)d_in[0];
    const int*   ei    = (const int*)d_in[1];
    const int*   batch = (const int*)d_in[2];
    const float* W1 = (const float*)d_in[3];  const float* b1 = (const float*)d_in[4];
    const float* W2 = (const float*)d_in[5];  const float* b2 = (const float*)d_in[6];
    const float* W3 = (const float*)d_in[7];  const float* b3 = (const float*)d_in[8];
    const float* W4 = (const float*)d_in[9];  const float* b4 = (const float*)d_in[10];
    const float* W5 = (const float*)d_in[11]; const float* b5 = (const float*)d_in[12];
    const float* W6 = (const float*)d_in[13]; const float* b6 = (const float*)d_in[14];
    float* out = (float*)d_out;

    const int N = in_sizes[0] / 2;       // 100000
    const int E = in_sizes[1] / 2;       // 1600000
    const int G = out_size / 10;         // 512

    // workspace layout (~90 MB)
    char* p = (char*)d_ws;
    auto take = [&](size_t bytes) -> void* {
        void* r = (void*)p;
        p += (bytes + 255) & ~(size_t)255;
        return r;
    };
    int*   bktCur   = (int*)take(NBKT * 4);
    int*   arena    = (int*)take((size_t)NBKT * BCAP * 4);   // 8 MB
    int*   csr_src  = (int*)take((size_t)NBKT * BCAP * 4);   // 8 MB
    float* dis      = (float*)take((size_t)N * 4);
    int2*  meta     = (int2*)take((size_t)N * 8);
    float* g0       = (float*)take((size_t)N * 2 * 4);
    float* g1       = (float*)take((size_t)N * 16 * 4);
    float* g2       = (float*)take((size_t)N * 32 * 4);
    float* g3       = (float*)take((size_t)N * 64 * 4);
    float* aggb     = (float*)take((size_t)N * 64 * 4);
    float* pooled   = (float*)take((size_t)G * 128 * 4);

    hipMemsetAsync(bktCur, 0, NBKT * 4, stream);
    hipMemsetAsync(pooled, 0, (size_t)G * 128 * 4, stream);

    const int PBLK = (E + EPB - 1) / EPB;    // 391
    partition_kernel<<<PBLK, 256, 0, stream>>>(ei, E, bktCur, arena);
    bucket_csr_kernel<<<NBKT, 512, 0, stream>>>(arena, bktCur, csr_src, meta, dis, x, g0, N);

    gcn_l1<<<2048, 256, 0, stream>>>(g0, meta, csr_src, dis, W1, b1, g1, N, 2048 * 4);

    const int ABLK = (N + 3) / 4;        // 4 waves per 256-thr block, 1 node each
    const int GBLK = (N + 63) / 64;      // 64-node GEMM tiles

    agg_kernel<16><<<ABLK, 256, 0, stream>>>(g1, meta, csr_src, dis, aggb, N);
    gemm_kernel<16, 32, false><<<GBLK, 256, 0, stream>>>(aggb, W2, b2, dis, g2, nullptr, nullptr, N);

    agg_kernel<32><<<ABLK, 256, 0, stream>>>(g2, meta, csr_src, dis, aggb, N);
    gemm_kernel<32, 64, false><<<GBLK, 256, 0, stream>>>(aggb, W3, b3, dis, g3, nullptr, nullptr, N);

    agg_kernel<64><<<ABLK, 256, 0, stream>>>(g3, meta, csr_src, dis, aggb, N);
    gemm_kernel<64, 128, true><<<GBLK, 256, 0, stream>>>(aggb, W4, b4, dis, nullptr, batch, pooled, N);

    mlp_kernel<<<G, 64, 0, stream>>>(pooled, W5, b5, W6, b6, out);
}

// Round 15
// 247.584 us; speedup vs baseline: 1.0781x; 1.0781x over previous
//
#include <hip/hip_runtime.h>
#include <hip/hip_fp16.h>

typedef __attribute__((ext_vector_type(4))) float f32x4;
typedef __attribute__((ext_vector_type(4))) int i32x4;

#define EPB 4096      // edges per partition block
#define NBKT 196      // ceil(100000/512) buckets of 512 nodes
#define BCAP 10240    // arena capacity per bucket (mean 8192, +22 sigma)

// =============== Phase B: partition edges into per-bucket arenas ================
__global__ __launch_bounds__(256)
void partition_kernel(const int* __restrict__ ei, int E,
                      int* __restrict__ bktCur, int* __restrict__ arena) {
    __shared__ int sHist[256];
    __shared__ int sScan[256];
    __shared__ int sAdj[256];
    __shared__ int2 sEdges[EPB];     // 32 KB staging
    const int t = threadIdx.x;
    const int e0 = blockIdx.x * EPB;
    const int ecnt = min(EPB, E - e0);
    const int* src = ei;
    const int* dst = ei + E;

    sHist[t] = 0;
    __syncthreads();
    for (int k = t; k < ecnt; k += 256) {
        const int s = src[e0 + k], d = dst[e0 + k];
        sEdges[k] = make_int2(s, d);
        atomicAdd(&sHist[d >> 9], 1);
    }
    __syncthreads();
    const int v = sHist[t];
    sScan[t] = v;
    __syncthreads();
    #pragma unroll
    for (int off = 1; off < 256; off <<= 1) {
        const int y = (t >= off) ? sScan[t - off] : 0;
        __syncthreads();
        sScan[t] += y;
        __syncthreads();
    }
    const int excl = sScan[t] - v;
    if (t < NBKT && v > 0) {
        const int g = atomicAdd(&bktCur[t], v);
        sAdj[t] = t * BCAP + g - excl;
    }
    sHist[t] = excl;
    __syncthreads();
    for (int k = t; k < ecnt; k += 256) {
        const int2 e = sEdges[k];
        const int b = e.y >> 9;
        const int p = atomicAdd(&sHist[b], 1);
        arena[sAdj[b] + p] = (e.x << 9) | (e.y & 511);
    }
}

// =============== Phase C: per-bucket CSR build + meta + dis + g0 = dis*x =========
__global__ __launch_bounds__(512)
void bucket_csr_kernel(const int* __restrict__ arena, const int* __restrict__ bktCur,
                       int* __restrict__ csr_src, int2* __restrict__ meta,
                       float* __restrict__ dis, const float* __restrict__ x,
                       float* __restrict__ g0, int n) {
    __shared__ int sHist[512];
    __shared__ int sScan[512];
    const int t = threadIdx.x;
    const int b = blockIdx.x;
    const int base = b * BCAP;
    const int cnt_b = min(bktCur[b], BCAP);

    sHist[t] = 0;
    __syncthreads();
    for (int e = t; e < cnt_b; e += 512)
        atomicAdd(&sHist[arena[base + e] & 511], 1);
    __syncthreads();
    const int v = sHist[t];
    sScan[t] = v;
    __syncthreads();
    #pragma unroll
    for (int off = 1; off < 512; off <<= 1) {
        const int y = (t >= off) ? sScan[t - off] : 0;
        __syncthreads();
        sScan[t] += y;
        __syncthreads();
    }
    const int excl = sScan[t] - v;
    const int node = b * 512 + t;
    if (node < n) {
        meta[node] = make_int2(base + excl, v);
        const float d = (float)(1.0 / sqrt((double)(v + 1)));
        dis[node] = d;
        float2 xv = *(const float2*)(x + 2 * (size_t)node);
        xv.x *= d; xv.y *= d;
        *(float2*)(g0 + 2 * (size_t)node) = xv;
    }
    sHist[t] = excl;
    __syncthreads();
    for (int e = t; e < cnt_b; e += 512) {
        const int pv = arena[base + e];
        const int p = atomicAdd(&sHist[pv & 511], 1);
        csr_src[base + p] = pv >> 9;
    }
}

// =============== Layer 1: [N,2] -> g1[N,16] (f32). Wave per node. ================
__global__ __launch_bounds__(256, 4)
void gcn_l1(const float* __restrict__ g0, const int2* __restrict__ meta,
            const int* __restrict__ csr_src, const float* __restrict__ dis,
            const float* __restrict__ W, const float* __restrict__ B,
            float* __restrict__ g1, int n, int nwaves) {
    const int lane = threadIdx.x & 63;
    const int wid = blockIdx.x * (blockDim.x >> 6) + (threadIdx.x >> 6);
    const int chunk = (n + nwaves - 1) / nwaves;
    const int n0 = wid * chunk, n1 = min(n0 + chunk, n);
    const int o = lane & 15;
    const float w0 = W[o], w1 = W[16 + o], bo = B[o];
    for (int node = n0; node < n1; ++node) {
        const int2 mt = meta[node];
        const int start = mt.x, m = mt.y;
        float a0 = 0.f, a1 = 0.f;
        for (int j = lane; j < m; j += 64) {
            const int s2 = csr_src[start + j];
            const float2 hv = *(const float2*)(g0 + 2 * (size_t)s2);
            a0 += hv.x;
            a1 += hv.y;
        }
        #pragma unroll
        for (int off = 32; off >= 1; off >>= 1) {
            a0 += __shfl_xor(a0, off);
            a1 += __shfl_xor(a1, off);
        }
        const float d0 = dis[node];
        const float2 hs = *(const float2*)(g0 + 2 * (size_t)node);
        a0 = (a0 + hs.x) * d0;
        a1 = (a1 + hs.y) * d0;
        if (lane < 16) {
            const float v = fmaxf(fmaf(a0, w0, fmaf(a1, w1, bo)), 0.f);
            g1[(size_t)node * 16 + o] = d0 * v;
        }
    }
}

// =============== AGG (f32 table, C=16): unchanged R13 structure. ================
template <int C_IN>
__global__ __launch_bounds__(256, 6)
void agg_kernel(const float* __restrict__ g_in, const int2* __restrict__ meta,
                const int* __restrict__ csr_src, const float* __restrict__ dis,
                float* __restrict__ agg, int n) {
    constexpr int LPR = C_IN / 4;
    constexpr int EPW = 64 / LPR;
    constexpr int LOGL = (LPR == 4) ? 2 : (LPR == 8) ? 3 : 4;
    constexpr int UNROLL = 32 / EPW;

    const int lane = threadIdx.x & 63;
    const int node = blockIdx.x * 4 + (threadIdx.x >> 6);
    if (node >= n) return;

    const int2 mt = meta[node];
    const int start = mt.x, m = mt.y;
    const int cb = (lane & (LPR - 1)) * 4;
    const int sub = lane >> LOGL;

    float ax = 0.f, ay = 0.f, az = 0.f, aw = 0.f;
    for (int j = sub; j < m; j += UNROLL * EPW) {
        int ss[UNROLL];
        float mm[UNROLL];
        #pragma unroll
        for (int u = 0; u < UNROLL; ++u) {
            const int jj = j + u * EPW;
            const bool ok = jj < m;
            ss[u] = csr_src[start + (ok ? jj : 0)];
            mm[u] = ok ? 1.f : 0.f;
        }
        f32x4 hv[UNROLL];
        const float* ap[UNROLL];
        #pragma unroll
        for (int u = 0; u < UNROLL; ++u) ap[u] = g_in + (size_t)ss[u] * C_IN + cb;
        #pragma unroll
        for (int u = 0; u < UNROLL; ++u)
            asm volatile("global_load_dwordx4 %0, %1, off"
                         : "=v"(hv[u]) : "v"(ap[u]) : "memory");
        asm volatile("s_waitcnt vmcnt(0)" ::: "memory");
        __builtin_amdgcn_sched_barrier(0);             // rule #18
        #pragma unroll
        for (int u = 0; u < UNROLL; ++u) {
            ax = fmaf(mm[u], hv[u].x, ax); ay = fmaf(mm[u], hv[u].y, ay);
            az = fmaf(mm[u], hv[u].z, az); aw = fmaf(mm[u], hv[u].w, aw);
        }
    }
    #pragma unroll
    for (int off = 32; off >= LPR; off >>= 1) {
        ax += __shfl_xor(ax, off); ay += __shfl_xor(ay, off);
        az += __shfl_xor(az, off); aw += __shfl_xor(aw, off);
    }
    if (lane < LPR) {
        const f32x4 hs = *(const f32x4*)(g_in + (size_t)node * C_IN + cb);
        const float d0 = dis[node];
        ax = (ax + hs.x) * d0; ay = (ay + hs.y) * d0;
        az = (az + hs.z) * d0; aw = (aw + hs.w) * d0;
        f32x4 t; t.x = ax; t.y = ay; t.z = az; t.w = aw;
        *(f32x4*)&agg[(size_t)node * C_IN + cb] = t;
    }
}

// =============== AGG (fp16 table, C=32/64): halves compulsory fabric bytes. ======
// Lane covers 8 channels (16B load) -> LPR halves, edges-in-flight doubles.
template <int C_IN>
__global__ __launch_bounds__(256, 6)
void agg_half_kernel(const __half* __restrict__ g_in, const int2* __restrict__ meta,
                     const int* __restrict__ csr_src, const float* __restrict__ dis,
                     float* __restrict__ agg, int n) {
    constexpr int LPR = C_IN / 8;                      // 4 (C32), 8 (C64)
    constexpr int EPW = 64 / LPR;                      // 16, 8
    constexpr int LOGL = (LPR == 4) ? 2 : 3;
    constexpr int UNROLL = 32 / EPW;                   // 2, 4

    const int lane = threadIdx.x & 63;
    const int node = blockIdx.x * 4 + (threadIdx.x >> 6);
    if (node >= n) return;

    const int2 mt = meta[node];
    const int start = mt.x, m = mt.y;
    const int cb = (lane & (LPR - 1)) * 8;             // channel base (halves)
    const int sub = lane >> LOGL;

    float a[8];
    #pragma unroll
    for (int q = 0; q < 8; ++q) a[q] = 0.f;

    for (int j = sub; j < m; j += UNROLL * EPW) {
        int ss[UNROLL];
        float mm[UNROLL];
        #pragma unroll
        for (int u = 0; u < UNROLL; ++u) {
            const int jj = j + u * EPW;
            const bool ok = jj < m;
            ss[u] = csr_src[start + (ok ? jj : 0)];
            mm[u] = ok ? 1.f : 0.f;
        }
        i32x4 hr[UNROLL];
        const __half* ap[UNROLL];
        #pragma unroll
        for (int u = 0; u < UNROLL; ++u) ap[u] = g_in + (size_t)ss[u] * C_IN + cb;
        #pragma unroll
        for (int u = 0; u < UNROLL; ++u)
            asm volatile("global_load_dwordx4 %0, %1, off"
                         : "=v"(hr[u]) : "v"(ap[u]) : "memory");
        asm volatile("s_waitcnt vmcnt(0)" ::: "memory");
        __builtin_amdgcn_sched_barrier(0);             // rule #18
        #pragma unroll
        for (int u = 0; u < UNROLL; ++u) {
            #pragma unroll
            for (int q = 0; q < 4; ++q) {
                const int wbits = hr[u][q];
                const __half2 h2 = *(const __half2*)&wbits;
                const float2 f2 = __half22float2(h2);
                a[2 * q]     = fmaf(mm[u], f2.x, a[2 * q]);
                a[2 * q + 1] = fmaf(mm[u], f2.y, a[2 * q + 1]);
            }
        }
    }
    #pragma unroll
    for (int off = 32; off >= LPR; off >>= 1) {
        #pragma unroll
        for (int q = 0; q < 8; ++q) a[q] += __shfl_xor(a[q], off);
    }
    if (lane < LPR) {
        const float d0 = dis[node];
        const __half* hp = g_in + (size_t)node * C_IN + cb;
        #pragma unroll
        for (int q = 0; q < 4; ++q) {
            const __half2 h2 = *(const __half2*)(hp + 2 * q);
            const float2 f2 = __half22float2(h2);
            a[2 * q]     = (a[2 * q]     + f2.x) * d0;
            a[2 * q + 1] = (a[2 * q + 1] + f2.y) * d0;
        }
        f32x4 t0, t1;
        t0.x = a[0]; t0.y = a[1]; t0.z = a[2]; t0.w = a[3];
        t1.x = a[4]; t1.y = a[5]; t1.z = a[6]; t1.w = a[7];
        *(f32x4*)&agg[(size_t)node * C_IN + cb] = t0;
        *(f32x4*)&agg[(size_t)node * C_IN + cb + 4] = t1;
    }
}

// =============== GEMM: out = dis*relu(agg @ W + B); optionally fp16 out / pool. ==
template <int C_IN, int C_OUT, bool FPOOL, bool OUT_HALF>
__global__ __launch_bounds__(256, 3)
void gemm_kernel(const float* __restrict__ agg, const float* __restrict__ W,
                 const float* __restrict__ Bias, const float* __restrict__ dis,
                 void* __restrict__ g_out_v, const int* __restrict__ batchv,
                 float* __restrict__ pooled, int n) {
    constexpr int QW = C_OUT / 16;
    constexpr int RPT = QW;
    constexpr int LOGQ = (QW == 8) ? 3 : (QW == 4) ? 2 : 1;
    constexpr int CH = C_IN / 4;
    constexpr int SA = 68;
    constexpr int SP = 133;

    constexpr int W_BYTES = C_IN * C_OUT * 4 + C_OUT * 4;
    constexpr int P_BYTES = FPOOL ? (64 * SP * 4) : 0;
    constexpr int R1 = ((W_BYTES > P_BYTES ? W_BYTES : P_BYTES) + 15) & ~15;
    constexpr int AT_BYTES = C_IN * SA * 4;
    __shared__ char smem[R1 + AT_BYTES];
    __shared__ int sGb[64];
    __shared__ float sDis[64];

    float* sW = (float*)smem;
    float* sB = sW + C_IN * C_OUT;
    float* sP = (float*)smem;
    float* sAt = (float*)(smem + R1);

    const int tid = threadIdx.x;
    const int base = blockIdx.x * 64;

    for (int i = tid; i < C_IN * C_OUT / 4; i += 256)
        ((f32x4*)sW)[i] = ((const f32x4*)W)[i];
    if (tid < C_OUT) sB[tid] = Bias[tid];
    {
        constexpr int RPP = 256 / CH;
        const int r = tid / CH, c0 = tid % CH;
        #pragma unroll
        for (int p = 0; p < 64 / RPP; ++p) {
            const int rr = p * RPP + r;
            const int node = base + rr;
            f32x4 v = {0.f, 0.f, 0.f, 0.f};
            if (node < n) v = *(const f32x4*)&agg[(size_t)node * C_IN + c0 * 4];
            sAt[(c0 * 4 + 0) * SA + rr] = v.x;
            sAt[(c0 * 4 + 1) * SA + rr] = v.y;
            sAt[(c0 * 4 + 2) * SA + rr] = v.z;
            sAt[(c0 * 4 + 3) * SA + rr] = v.w;
        }
    }
    if (FPOOL && tid < 64) sGb[tid] = (base + tid < n) ? batchv[base + tid] : -1;
    if (!FPOOL && tid < 64) sDis[tid] = (base + tid < n) ? dis[base + tid] : 0.f;
    __syncthreads();

    const int w = tid >> 6, l = tid & 63;
    const int j = l & (QW - 1);
    const int rg = l >> LOGQ;
    const int ob = w * (C_OUT / 4) + j * 4;

    f32x4 acc[RPT];
    {
        const f32x4 bv = *(const f32x4*)&sB[ob];
        #pragma unroll
        for (int r = 0; r < RPT; ++r) acc[r] = bv;
    }

    #pragma unroll 4
    for (int k = 0; k < C_IN; ++k) {
        const f32x4 wv = ((const f32x4*)sW)[k * (C_OUT / 4) + (ob >> 2)];
        float av[RPT];
        if constexpr (RPT == 8) {
            const f32x4 a0 = *(const f32x4*)&sAt[k * SA + rg * 8];
            const f32x4 a1 = *(const f32x4*)&sAt[k * SA + rg * 8 + 4];
            av[0] = a0.x; av[1] = a0.y; av[2] = a0.z; av[3] = a0.w;
            av[4] = a1.x; av[5] = a1.y; av[6] = a1.z; av[7] = a1.w;
        } else if constexpr (RPT == 4) {
            const f32x4 a0 = *(const f32x4*)&sAt[k * SA + rg * 4];
            av[0] = a0.x; av[1] = a0.y; av[2] = a0.z; av[3] = a0.w;
        } else {
            const float2 a0 = *(const float2*)&sAt[k * SA + rg * 2];
            av[0] = a0.x; av[1] = a0.y;
        }
        #pragma unroll
        for (int r = 0; r < RPT; ++r) {
            acc[r].x = fmaf(av[r], wv.x, acc[r].x);
            acc[r].y = fmaf(av[r], wv.y, acc[r].y);
            acc[r].z = fmaf(av[r], wv.z, acc[r].z);
            acc[r].w = fmaf(av[r], wv.w, acc[r].w);
        }
    }

    if constexpr (!FPOOL) {
        #pragma unroll
        for (int r = 0; r < RPT; ++r) {
            const int row = rg * RPT + r;
            const int node = base + row;
            if (node < n) {
                const float sd = sDis[row];
                const float o0 = sd * fmaxf(acc[r].x, 0.f);
                const float o1 = sd * fmaxf(acc[r].y, 0.f);
                const float o2 = sd * fmaxf(acc[r].z, 0.f);
                const float o3 = sd * fmaxf(acc[r].w, 0.f);
                if constexpr (OUT_HALF) {
                    __half2 lo = __floats2half2_rn(o0, o1);
                    __half2 hi = __floats2half2_rn(o2, o3);
                    uint2 pk;
                    pk.x = *(unsigned int*)&lo;
                    pk.y = *(unsigned int*)&hi;
                    *(uint2*)((__half*)g_out_v + (size_t)node * C_OUT + ob) = pk;
                } else {
                    f32x4 o; o.x = o0; o.y = o1; o.z = o2; o.w = o3;
                    *(f32x4*)((float*)g_out_v + (size_t)node * C_OUT + ob) = o;
                }
            }
        }
    } else {
        __syncthreads();
        #pragma unroll
        for (int r = 0; r < RPT; ++r) {
            const int row = rg * RPT + r;
            sP[row * SP + ob + 0] = fmaxf(acc[r].x, 0.f);
            sP[row * SP + ob + 1] = fmaxf(acc[r].y, 0.f);
            sP[row * SP + ob + 2] = fmaxf(acc[r].z, 0.f);
            sP[row * SP + ob + 3] = fmaxf(acc[r].w, 0.f);
        }
        __syncthreads();
        if (tid < 128) {
            const int c = tid;
            int curg = -1; float run = 0.f;
            for (int r = 0; r < 64; ++r) {
                const int gb = sGb[r];
                if (gb < 0) continue;
                const float v = sP[r * SP + c];
                if (gb != curg) {
                    if (curg >= 0)
                        atomicMax((int*)&pooled[(size_t)curg * 128 + c], __float_as_int(run));
                    curg = gb; run = v;
                } else {
                    run = fmaxf(run, v);
                }
            }
            if (curg >= 0)
                atomicMax((int*)&pooled[(size_t)curg * 128 + c], __float_as_int(run));
        }
    }
}

// ---------------- MLP head: relu(pooled @ W5 + b5) @ W6 + b6 ----------------
__global__ void mlp_kernel(const float* __restrict__ pooled,
                           const float* __restrict__ W5, const float* __restrict__ b5,
                           const float* __restrict__ W6, const float* __restrict__ b6,
                           float* __restrict__ out) {
    const int g = blockIdx.x;
    const int t = threadIdx.x;  // 64 threads
    __shared__ float row[128];
    __shared__ float hid[64];
    row[t] = pooled[g * 128 + t];
    row[64 + t] = pooled[g * 128 + 64 + t];
    __syncthreads();
    float v = b5[t];
    #pragma unroll 8
    for (int c = 0; c < 128; ++c) v = fmaf(row[c], W5[c * 64 + t], v);
    hid[t] = fmaxf(v, 0.f);
    __syncthreads();
    if (t < 10) {
        float o = b6[t];
        #pragma unroll 8
        for (int c = 0; c < 64; ++c) o = fmaf(hid[c], W6[c * 10 + t], o);
        out[g * 10 + t] = o;
    }
}

extern "C" void kernel_launch(void* const* d_in, const int* in_sizes, int n_in,
                              void* d_out, int out_size, void* d_ws, size_t ws_size,
                              hipStream_t stream) {
    const float* x     = (const float*)d_in[0];
    const int*   ei    = (const int*)d_in[1];
    const int*   batch = (const int*)d_in[2];
    const float* W1 = (const float*)d_in[3];  const float* b1 = (const float*)d_in[4];
    const float* W2 = (const float*)d_in[5];  const float* b2 = (const float*)d_in[6];
    const float* W3 = (const float*)d_in[7];  const float* b3 = (const float*)d_in[8];
    const float* W4 = (const float*)d_in[9];  const float* b4 = (const float*)d_in[10];
    const float* W5 = (const float*)d_in[11]; const float* b5 = (const float*)d_in[12];
    const float* W6 = (const float*)d_in[13]; const float* b6 = (const float*)d_in[14];
    float* out = (float*)d_out;

    const int N = in_sizes[0] / 2;       // 100000
    const int E = in_sizes[1] / 2;       // 1600000
    const int G = out_size / 10;         // 512

    // workspace layout
    char* p = (char*)d_ws;
    auto take = [&](size_t bytes) -> void* {
        void* r = (void*)p;
        p += (bytes + 255) & ~(size_t)255;
        return r;
    };
    int*    bktCur = (int*)take(NBKT * 4);
    int*    arena  = (int*)take((size_t)NBKT * BCAP * 4);
    int*    csr_src= (int*)take((size_t)NBKT * BCAP * 4);
    float*  dis    = (float*)take((size_t)N * 4);
    int2*   meta   = (int2*)take((size_t)N * 8);
    float*  g0     = (float*)take((size_t)N * 2 * 4);
    float*  g1     = (float*)take((size_t)N * 16 * 4);
    __half* g2h    = (__half*)take((size_t)N * 32 * 2);
    __half* g3h    = (__half*)take((size_t)N * 64 * 2);
    float*  aggb   = (float*)take((size_t)N * 64 * 4);
    float*  pooled = (float*)take((size_t)G * 128 * 4);

    hipMemsetAsync(bktCur, 0, NBKT * 4, stream);
    hipMemsetAsync(pooled, 0, (size_t)G * 128 * 4, stream);

    const int PBLK = (E + EPB - 1) / EPB;    // 391
    partition_kernel<<<PBLK, 256, 0, stream>>>(ei, E, bktCur, arena);
    bucket_csr_kernel<<<NBKT, 512, 0, stream>>>(arena, bktCur, csr_src, meta, dis, x, g0, N);

    gcn_l1<<<2048, 256, 0, stream>>>(g0, meta, csr_src, dis, W1, b1, g1, N, 2048 * 4);

    const int ABLK = (N + 3) / 4;
    const int GBLK = (N + 63) / 64;

    agg_kernel<16><<<ABLK, 256, 0, stream>>>(g1, meta, csr_src, dis, aggb, N);
    gemm_kernel<16, 32, false, true><<<GBLK, 256, 0, stream>>>(aggb, W2, b2, dis, g2h, nullptr, nullptr, N);

    agg_half_kernel<32><<<ABLK, 256, 0, stream>>>(g2h, meta, csr_src, dis, aggb, N);
    gemm_kernel<32, 64, false, true><<<GBLK, 256, 0, stream>>>(aggb, W3, b3, dis, g3h, nullptr, nullptr, N);

    agg_half_kernel<64><<<ABLK, 256, 0, stream>>>(g3h, meta, csr_src, dis, aggb, N);
    gemm_kernel<64, 128, true, false><<<GBLK, 256, 0, stream>>>(aggb, W4, b4, dis, nullptr, batch, pooled, N);

    mlp_kernel<<<G, 64, 0, stream>>>(pooled, W5, b5, W6, b6, out);
}

// Round 16
// 228.085 us; speedup vs baseline: 1.1702x; 1.0855x over previous
//
#include <hip/hip_runtime.h>
#include <hip/hip_fp16.h>

typedef __attribute__((ext_vector_type(4))) float f32x4;
typedef __attribute__((ext_vector_type(4))) int i32x4;
typedef _Float16 f16x8 __attribute__((ext_vector_type(8)));
typedef _Float16 f16x4 __attribute__((ext_vector_type(4)));

#define EPB 4096      // edges per partition block
#define NBKT 196      // ceil(100000/512) buckets of 512 nodes
#define BCAP 10240    // arena capacity per bucket (mean 8192, +22 sigma)

// =============== Phase B: partition edges into per-bucket arenas ================
__global__ __launch_bounds__(256)
void partition_kernel(const int* __restrict__ ei, int E,
                      int* __restrict__ bktCur, int* __restrict__ arena) {
    __shared__ int sHist[256];
    __shared__ int sScan[256];
    __shared__ int sAdj[256];
    __shared__ int2 sEdges[EPB];     // 32 KB staging
    const int t = threadIdx.x;
    const int e0 = blockIdx.x * EPB;
    const int ecnt = min(EPB, E - e0);
    const int* src = ei;
    const int* dst = ei + E;

    sHist[t] = 0;
    __syncthreads();
    for (int k = t; k < ecnt; k += 256) {
        const int s = src[e0 + k], d = dst[e0 + k];
        sEdges[k] = make_int2(s, d);
        atomicAdd(&sHist[d >> 9], 1);
    }
    __syncthreads();
    const int v = sHist[t];
    sScan[t] = v;
    __syncthreads();
    #pragma unroll
    for (int off = 1; off < 256; off <<= 1) {
        const int y = (t >= off) ? sScan[t - off] : 0;
        __syncthreads();
        sScan[t] += y;
        __syncthreads();
    }
    const int excl = sScan[t] - v;
    if (t < NBKT && v > 0) {
        const int g = atomicAdd(&bktCur[t], v);
        sAdj[t] = t * BCAP + g - excl;
    }
    sHist[t] = excl;
    __syncthreads();
    for (int k = t; k < ecnt; k += 256) {
        const int2 e = sEdges[k];
        const int b = e.y >> 9;
        const int p = atomicAdd(&sHist[b], 1);
        arena[sAdj[b] + p] = (e.x << 9) | (e.y & 511);
    }
}

// =============== Phase C: per-bucket CSR build + meta + dis + g0 = dis*x =========
__global__ __launch_bounds__(512)
void bucket_csr_kernel(const int* __restrict__ arena, const int* __restrict__ bktCur,
                       int* __restrict__ csr_src, int2* __restrict__ meta,
                       float* __restrict__ dis, const float* __restrict__ x,
                       float* __restrict__ g0, int n) {
    __shared__ int sHist[512];
    __shared__ int sScan[512];
    const int t = threadIdx.x;
    const int b = blockIdx.x;
    const int base = b * BCAP;
    const int cnt_b = min(bktCur[b], BCAP);

    sHist[t] = 0;
    __syncthreads();
    for (int e = t; e < cnt_b; e += 512)
        atomicAdd(&sHist[arena[base + e] & 511], 1);
    __syncthreads();
    const int v = sHist[t];
    sScan[t] = v;
    __syncthreads();
    #pragma unroll
    for (int off = 1; off < 512; off <<= 1) {
        const int y = (t >= off) ? sScan[t - off] : 0;
        __syncthreads();
        sScan[t] += y;
        __syncthreads();
    }
    const int excl = sScan[t] - v;
    const int node = b * 512 + t;
    if (node < n) {
        meta[node] = make_int2(base + excl, v);
        const float d = (float)(1.0 / sqrt((double)(v + 1)));
        dis[node] = d;
        float2 xv = *(const float2*)(x + 2 * (size_t)node);
        xv.x *= d; xv.y *= d;
        *(float2*)(g0 + 2 * (size_t)node) = xv;
    }
    sHist[t] = excl;
    __syncthreads();
    for (int e = t; e < cnt_b; e += 512) {
        const int pv = arena[base + e];
        const int p = atomicAdd(&sHist[pv & 511], 1);
        csr_src[base + p] = pv >> 9;
    }
}

// =============== Prepack W4 -> fp16 MFMA B-fragment layout. =====================
// Fragment (derived from m156/m162 tr-read geometry): elem i of lane l holds
// B[k][n] with n = ct*16 + (l&15), k = kk*32 + 4*(l>>4) + (i&3) + 16*(i>>2).
__global__ void prepack_w4_kernel(const float* __restrict__ W, _Float16* __restrict__ Wpk) {
    const int t = blockIdx.x * 256 + threadIdx.x;   // 8192 total
    const int i = t & 7;
    const int l = (t >> 3) & 63;
    const int kk = (t >> 9) & 1;
    const int ct = t >> 10;
    const int k = kk * 32 + 4 * (l >> 4) + (i & 3) + 16 * (i >> 2);
    const int col = ct * 16 + (l & 15);
    Wpk[t] = (_Float16)W[k * 128 + col];
}

// =============== Layer 1: [N,2] -> g1[N,16] (f32). Wave per node. ================
__global__ __launch_bounds__(256, 4)
void gcn_l1(const float* __restrict__ g0, const int2* __restrict__ meta,
            const int* __restrict__ csr_src, const float* __restrict__ dis,
            const float* __restrict__ W, const float* __restrict__ B,
            float* __restrict__ g1, int n, int nwaves) {
    const int lane = threadIdx.x & 63;
    const int wid = blockIdx.x * (blockDim.x >> 6) + (threadIdx.x >> 6);
    const int chunk = (n + nwaves - 1) / nwaves;
    const int n0 = wid * chunk, n1 = min(n0 + chunk, n);
    const int o = lane & 15;
    const float w0 = W[o], w1 = W[16 + o], bo = B[o];
    for (int node = n0; node < n1; ++node) {
        const int2 mt = meta[node];
        const int start = mt.x, m = mt.y;
        float a0 = 0.f, a1 = 0.f;
        for (int j = lane; j < m; j += 64) {
            const int s2 = csr_src[start + j];
            const float2 hv = *(const float2*)(g0 + 2 * (size_t)s2);
            a0 += hv.x;
            a1 += hv.y;
        }
        #pragma unroll
        for (int off = 32; off >= 1; off >>= 1) {
            a0 += __shfl_xor(a0, off);
            a1 += __shfl_xor(a1, off);
        }
        const float d0 = dis[node];
        const float2 hs = *(const float2*)(g0 + 2 * (size_t)node);
        a0 = (a0 + hs.x) * d0;
        a1 = (a1 + hs.y) * d0;
        if (lane < 16) {
            const float v = fmaxf(fmaf(a0, w0, fmaf(a1, w1, bo)), 0.f);
            g1[(size_t)node * 16 + o] = d0 * v;
        }
    }
}

// =============== AGG (f32 table, C=16): unchanged R13 structure. ================
template <int C_IN>
__global__ __launch_bounds__(256, 6)
void agg_kernel(const float* __restrict__ g_in, const int2* __restrict__ meta,
                const int* __restrict__ csr_src, const float* __restrict__ dis,
                float* __restrict__ agg, int n) {
    constexpr int LPR = C_IN / 4;
    constexpr int EPW = 64 / LPR;
    constexpr int LOGL = (LPR == 4) ? 2 : (LPR == 8) ? 3 : 4;
    constexpr int UNROLL = 32 / EPW;

    const int lane = threadIdx.x & 63;
    const int node = blockIdx.x * 4 + (threadIdx.x >> 6);
    if (node >= n) return;

    const int2 mt = meta[node];
    const int start = mt.x, m = mt.y;
    const int cb = (lane & (LPR - 1)) * 4;
    const int sub = lane >> LOGL;

    float ax = 0.f, ay = 0.f, az = 0.f, aw = 0.f;
    for (int j = sub; j < m; j += UNROLL * EPW) {
        int ss[UNROLL];
        float mm[UNROLL];
        #pragma unroll
        for (int u = 0; u < UNROLL; ++u) {
            const int jj = j + u * EPW;
            const bool ok = jj < m;
            ss[u] = csr_src[start + (ok ? jj : 0)];
            mm[u] = ok ? 1.f : 0.f;
        }
        f32x4 hv[UNROLL];
        const float* ap[UNROLL];
        #pragma unroll
        for (int u = 0; u < UNROLL; ++u) ap[u] = g_in + (size_t)ss[u] * C_IN + cb;
        #pragma unroll
        for (int u = 0; u < UNROLL; ++u)
            asm volatile("global_load_dwordx4 %0, %1, off"
                         : "=v"(hv[u]) : "v"(ap[u]) : "memory");
        asm volatile("s_waitcnt vmcnt(0)" ::: "memory");
        __builtin_amdgcn_sched_barrier(0);             // rule #18
        #pragma unroll
        for (int u = 0; u < UNROLL; ++u) {
            ax = fmaf(mm[u], hv[u].x, ax); ay = fmaf(mm[u], hv[u].y, ay);
            az = fmaf(mm[u], hv[u].z, az); aw = fmaf(mm[u], hv[u].w, aw);
        }
    }
    #pragma unroll
    for (int off = 32; off >= LPR; off >>= 1) {
        ax += __shfl_xor(ax, off); ay += __shfl_xor(ay, off);
        az += __shfl_xor(az, off); aw += __shfl_xor(aw, off);
    }
    if (lane < LPR) {
        const f32x4 hs = *(const f32x4*)(g_in + (size_t)node * C_IN + cb);
        const float d0 = dis[node];
        ax = (ax + hs.x) * d0; ay = (ay + hs.y) * d0;
        az = (az + hs.z) * d0; aw = (aw + hs.w) * d0;
        f32x4 t; t.x = ax; t.y = ay; t.z = az; t.w = aw;
        *(f32x4*)&agg[(size_t)node * C_IN + cb] = t;
    }
}

// =============== AGG (fp16 table, C=32/64); optional fp16 agg output. ============
template <int C_IN, bool OUT_HALF>
__global__ __launch_bounds__(256, 6)
void agg_half_kernel(const __half* __restrict__ g_in, const int2* __restrict__ meta,
                     const int* __restrict__ csr_src, const float* __restrict__ dis,
                     void* __restrict__ agg_v, int n) {
    constexpr int LPR = C_IN / 8;                      // 4 (C32), 8 (C64)
    constexpr int EPW = 64 / LPR;                      // 16, 8
    constexpr int LOGL = (LPR == 4) ? 2 : 3;
    constexpr int UNROLL = 32 / EPW;                   // 2, 4

    const int lane = threadIdx.x & 63;
    const int node = blockIdx.x * 4 + (threadIdx.x >> 6);
    if (node >= n) return;

    const int2 mt = meta[node];
    const int start = mt.x, m = mt.y;
    const int cb = (lane & (LPR - 1)) * 8;
    const int sub = lane >> LOGL;

    float a[8];
    #pragma unroll
    for (int q = 0; q < 8; ++q) a[q] = 0.f;

    for (int j = sub; j < m; j += UNROLL * EPW) {
        int ss[UNROLL];
        float mm[UNROLL];
        #pragma unroll
        for (int u = 0; u < UNROLL; ++u) {
            const int jj = j + u * EPW;
            const bool ok = jj < m;
            ss[u] = csr_src[start + (ok ? jj : 0)];
            mm[u] = ok ? 1.f : 0.f;
        }
        i32x4 hr[UNROLL];
        const __half* ap[UNROLL];
        #pragma unroll
        for (int u = 0; u < UNROLL; ++u) ap[u] = g_in + (size_t)ss[u] * C_IN + cb;
        #pragma unroll
        for (int u = 0; u < UNROLL; ++u)
            asm volatile("global_load_dwordx4 %0, %1, off"
                         : "=v"(hr[u]) : "v"(ap[u]) : "memory");
        asm volatile("s_waitcnt vmcnt(0)" ::: "memory");
        __builtin_amdgcn_sched_barrier(0);             // rule #18
        #pragma unroll
        for (int u = 0; u < UNROLL; ++u) {
            #pragma unroll
            for (int q = 0; q < 4; ++q) {
                const int wbits = hr[u][q];
                const __half2 h2 = *(const __half2*)&wbits;
                const float2 f2 = __half22float2(h2);
                a[2 * q]     = fmaf(mm[u], f2.x, a[2 * q]);
                a[2 * q + 1] = fmaf(mm[u], f2.y, a[2 * q + 1]);
            }
        }
    }
    #pragma unroll
    for (int off = 32; off >= LPR; off >>= 1) {
        #pragma unroll
        for (int q = 0; q < 8; ++q) a[q] += __shfl_xor(a[q], off);
    }
    if (lane < LPR) {
        const float d0 = dis[node];
        const __half* hp = g_in + (size_t)node * C_IN + cb;
        #pragma unroll
        for (int q = 0; q < 4; ++q) {
            const __half2 h2 = *(const __half2*)(hp + 2 * q);
            const float2 f2 = __half22float2(h2);
            a[2 * q]     = (a[2 * q]     + f2.x) * d0;
            a[2 * q + 1] = (a[2 * q + 1] + f2.y) * d0;
        }
        if constexpr (OUT_HALF) {
            f16x8 t;
            #pragma unroll
            for (int q = 0; q < 8; ++q) t[q] = (_Float16)a[q];
            *(f16x8*)((_Float16*)agg_v + (size_t)node * C_IN + cb) = t;
        } else {
            float* agg = (float*)agg_v;
            f32x4 t0, t1;
            t0.x = a[0]; t0.y = a[1]; t0.z = a[2]; t0.w = a[3];
            t1.x = a[4]; t1.y = a[5]; t1.z = a[6]; t1.w = a[7];
            *(f32x4*)&agg[(size_t)node * C_IN + cb] = t0;
            *(f32x4*)&agg[(size_t)node * C_IN + cb + 4] = t1;
        }
    }
}

// =============== GEMM (scalar, layers 2-3): out = dis*relu(agg @ W + B). =========
template <int C_IN, int C_OUT, bool OUT_HALF>
__global__ __launch_bounds__(256, 3)
void gemm_kernel(const float* __restrict__ agg, const float* __restrict__ W,
                 const float* __restrict__ Bias, const float* __restrict__ dis,
                 void* __restrict__ g_out_v, int n) {
    constexpr int QW = C_OUT / 16;
    constexpr int RPT = QW;
    constexpr int LOGQ = (QW == 8) ? 3 : (QW == 4) ? 2 : 1;
    constexpr int CH = C_IN / 4;
    constexpr int SA = 68;

    constexpr int W_BYTES = C_IN * C_OUT * 4 + C_OUT * 4;
    constexpr int R1 = (W_BYTES + 15) & ~15;
    constexpr int AT_BYTES = C_IN * SA * 4;
    __shared__ char smem[R1 + AT_BYTES];
    __shared__ float sDis[64];

    float* sW = (float*)smem;
    float* sB = sW + C_IN * C_OUT;
    float* sAt = (float*)(smem + R1);

    const int tid = threadIdx.x;
    const int base = blockIdx.x * 64;

    for (int i = tid; i < C_IN * C_OUT / 4; i += 256)
        ((f32x4*)sW)[i] = ((const f32x4*)W)[i];
    if (tid < C_OUT) sB[tid] = Bias[tid];
    {
        constexpr int RPP = 256 / CH;
        const int r = tid / CH, c0 = tid % CH;
        #pragma unroll
        for (int p = 0; p < 64 / RPP; ++p) {
            const int rr = p * RPP + r;
            const int node = base + rr;
            f32x4 v = {0.f, 0.f, 0.f, 0.f};
            if (node < n) v = *(const f32x4*)&agg[(size_t)node * C_IN + c0 * 4];
            sAt[(c0 * 4 + 0) * SA + rr] = v.x;
            sAt[(c0 * 4 + 1) * SA + rr] = v.y;
            sAt[(c0 * 4 + 2) * SA + rr] = v.z;
            sAt[(c0 * 4 + 3) * SA + rr] = v.w;
        }
    }
    if (tid < 64) sDis[tid] = (base + tid < n) ? dis[base + tid] : 0.f;
    __syncthreads();

    const int w = tid >> 6, l = tid & 63;
    const int j = l & (QW - 1);
    const int rg = l >> LOGQ;
    const int ob = w * (C_OUT / 4) + j * 4;

    f32x4 acc[RPT];
    {
        const f32x4 bv = *(const f32x4*)&sB[ob];
        #pragma unroll
        for (int r = 0; r < RPT; ++r) acc[r] = bv;
    }

    #pragma unroll 4
    for (int k = 0; k < C_IN; ++k) {
        const f32x4 wv = ((const f32x4*)sW)[k * (C_OUT / 4) + (ob >> 2)];
        float av[RPT];
        if constexpr (RPT == 4) {
            const f32x4 a0 = *(const f32x4*)&sAt[k * SA + rg * 4];
            av[0] = a0.x; av[1] = a0.y; av[2] = a0.z; av[3] = a0.w;
        } else {
            const float2 a0 = *(const float2*)&sAt[k * SA + rg * 2];
            av[0] = a0.x; av[1] = a0.y;
        }
        #pragma unroll
        for (int r = 0; r < RPT; ++r) {
            acc[r].x = fmaf(av[r], wv.x, acc[r].x);
            acc[r].y = fmaf(av[r], wv.y, acc[r].y);
            acc[r].z = fmaf(av[r], wv.z, acc[r].z);
            acc[r].w = fmaf(av[r], wv.w, acc[r].w);
        }
    }

    #pragma unroll
    for (int r = 0; r < RPT; ++r) {
        const int row = rg * RPT + r;
        const int node = base + row;
        if (node < n) {
            const float sd = sDis[row];
            const float o0 = sd * fmaxf(acc[r].x, 0.f);
            const float o1 = sd * fmaxf(acc[r].y, 0.f);
            const float o2 = sd * fmaxf(acc[r].z, 0.f);
            const float o3 = sd * fmaxf(acc[r].w, 0.f);
            if constexpr (OUT_HALF) {
                __half2 lo = __floats2half2_rn(o0, o1);
                __half2 hi = __floats2half2_rn(o2, o3);
                uint2 pk;
                pk.x = *(unsigned int*)&lo;
                pk.y = *(unsigned int*)&hi;
                *(uint2*)((__half*)g_out_v + (size_t)node * C_OUT + ob) = pk;
            } else {
                f32x4 o; o.x = o0; o.y = o1; o.z = o2; o.w = o3;
                *(f32x4*)((float*)g_out_v + (size_t)node * C_OUT + ob) = o;
            }
        }
    }
}

// =============== Layer-4 GEMM via MFMA + fused max-pool. ==========================
// Per wave: 16 nodes x 128 outs, K=64 -> 16 x mfma_f32_16x16x32_f16.
// A frag: agg rows fp16; elem i of lane l: k = 4*(l>>4)+(i&3)+16*(i>>2).
// B frag: prepacked Wpk (consistent by construction). C/D: col=lane&15,
// row=(lane>>4)*4+reg [m89-verified].
__global__ __launch_bounds__(256)
void gemm4_mfma_kernel(const _Float16* __restrict__ aggh, const _Float16* __restrict__ Wpk,
                       const float* __restrict__ Bias, const int* __restrict__ batchv,
                       float* __restrict__ pooled, int n) {
    __shared__ float sP[4][16][132];
    __shared__ int sGb[64];

    const int tid = threadIdx.x;
    const int w = tid >> 6, l = tid & 63;
    const int base = blockIdx.x * 64;

    if (tid < 64) sGb[tid] = (base + tid < n) ? batchv[base + tid] : -1;

    int node_a = base + w * 16 + (l & 15);
    if (node_a >= n) node_a = n - 1;                  // clamped rows pooled-guarded later
    const int kb = l >> 4;
    const f16x4* rowp = (const f16x4*)(aggh + (size_t)node_a * 64);
    const f16x4 a00 = rowp[kb];                       // k = 4kb+0..3
    const f16x4 a01 = rowp[4 + kb];                   // k = 16+4kb+0..3
    const f16x4 a10 = rowp[8 + kb];                   // k = 32+4kb+0..3
    const f16x4 a11 = rowp[12 + kb];                  // k = 48+4kb+0..3
    const f16x8 a0 = __builtin_shufflevector(a00, a01, 0, 1, 2, 3, 4, 5, 6, 7);
    const f16x8 a1 = __builtin_shufflevector(a10, a11, 0, 1, 2, 3, 4, 5, 6, 7);

    f32x4 acc[8];
    #pragma unroll
    for (int ct = 0; ct < 8; ++ct) {
        f32x4 z = {0.f, 0.f, 0.f, 0.f};
        const f16x8 b0 = *(const f16x8*)(Wpk + ((ct * 2 + 0) * 64 + l) * 8);
        const f16x8 b1 = *(const f16x8*)(Wpk + ((ct * 2 + 1) * 64 + l) * 8);
        z = __builtin_amdgcn_mfma_f32_16x16x32_f16(a0, b0, z, 0, 0, 0);
        z = __builtin_amdgcn_mfma_f32_16x16x32_f16(a1, b1, z, 0, 0, 0);
        acc[ct] = z;
    }

    // epilogue: bias + relu -> LDS tile
    #pragma unroll
    for (int ct = 0; ct < 8; ++ct) {
        const float b = Bias[ct * 16 + (l & 15)];
        #pragma unroll
        for (int r = 0; r < 4; ++r) {
            const int m = (l >> 4) * 4 + r;           // node within wave tile
            sP[w][m][ct * 16 + (l & 15)] = fmaxf(acc[ct][r] + b, 0.f);
        }
    }
    __syncthreads();

    if (tid < 128) {                                  // run-pool over the 64-node tile
        const int c = tid;
        int curg = -1; float run = 0.f;
        for (int r2 = 0; r2 < 64; ++r2) {
            const int gb = sGb[r2];
            if (gb < 0) continue;
            const float v = sP[r2 >> 4][r2 & 15][c];
            if (gb != curg) {
                if (curg >= 0)
                    atomicMax((int*)&pooled[(size_t)curg * 128 + c], __float_as_int(run));
                curg = gb; run = v;
            } else {
                run = fmaxf(run, v);
            }
        }
        if (curg >= 0)
            atomicMax((int*)&pooled[(size_t)curg * 128 + c], __float_as_int(run));
    }
}

// ---------------- MLP head: relu(pooled @ W5 + b5) @ W6 + b6 ----------------
__global__ void mlp_kernel(const float* __restrict__ pooled,
                           const float* __restrict__ W5, const float* __restrict__ b5,
                           const float* __restrict__ W6, const float* __restrict__ b6,
                           float* __restrict__ out) {
    const int g = blockIdx.x;
    const int t = threadIdx.x;  // 64 threads
    __shared__ float row[128];
    __shared__ float hid[64];
    row[t] = pooled[g * 128 + t];
    row[64 + t] = pooled[g * 128 + 64 + t];
    __syncthreads();
    float v = b5[t];
    #pragma unroll 8
    for (int c = 0; c < 128; ++c) v = fmaf(row[c], W5[c * 64 + t], v);
    hid[t] = fmaxf(v, 0.f);
    __syncthreads();
    if (t < 10) {
        float o = b6[t];
        #pragma unroll 8
        for (int c = 0; c < 64; ++c) o = fmaf(hid[c], W6[c * 10 + t], o);
        out[g * 10 + t] = o;
    }
}

extern "C" void kernel_launch(void* const* d_in, const int* in_sizes, int n_in,
                              void* d_out, int out_size, void* d_ws, size_t ws_size,
                              hipStream_t stream) {
    const float* x     = (const float*)d_in[0];
    const int*   ei    = (const int*)d_in[1];
    const int*   batch = (const int*)d_in[2];
    const float* W1 = (const float*)d_in[3];  const float* b1 = (const float*)d_in[4];
    const float* W2 = (const float*)d_in[5];  const float* b2 = (const float*)d_in[6];
    const float* W3 = (const float*)d_in[7];  const float* b3 = (const float*)d_in[8];
    const float* W4 = (const float*)d_in[9];  const float* b4 = (const float*)d_in[10];
    const float* W5 = (const float*)d_in[11]; const float* b5 = (const float*)d_in[12];
    const float* W6 = (const float*)d_in[13]; const float* b6 = (const float*)d_in[14];
    float* out = (float*)d_out;

    const int N = in_sizes[0] / 2;       // 100000
    const int E = in_sizes[1] / 2;       // 1600000
    const int G = out_size / 10;         // 512

    // workspace layout
    char* p = (char*)d_ws;
    auto take = [&](size_t bytes) -> void* {
        void* r = (void*)p;
        p += (bytes + 255) & ~(size_t)255;
        return r;
    };
    int*       bktCur = (int*)take(NBKT * 4);
    int*       arena  = (int*)take((size_t)NBKT * BCAP * 4);
    int*       csr_src= (int*)take((size_t)NBKT * BCAP * 4);
    float*     dis    = (float*)take((size_t)N * 4);
    int2*      meta   = (int2*)take((size_t)N * 8);
    float*     g0     = (float*)take((size_t)N * 2 * 4);
    float*     g1     = (float*)take((size_t)N * 16 * 4);
    __half*    g2h    = (__half*)take((size_t)N * 32 * 2);
    __half*    g3h    = (__half*)take((size_t)N * 64 * 2);
    float*     aggb   = (float*)take((size_t)N * 32 * 4);
    _Float16*  aggh   = (_Float16*)take((size_t)N * 64 * 2);
    _Float16*  Wpk    = (_Float16*)take(8192 * 2);
    float*     pooled = (float*)take((size_t)G * 128 * 4);

    hipMemsetAsync(bktCur, 0, NBKT * 4, stream);
    hipMemsetAsync(pooled, 0, (size_t)G * 128 * 4, stream);

    const int PBLK = (E + EPB - 1) / EPB;    // 391
    partition_kernel<<<PBLK, 256, 0, stream>>>(ei, E, bktCur, arena);
    bucket_csr_kernel<<<NBKT, 512, 0, stream>>>(arena, bktCur, csr_src, meta, dis, x, g0, N);

    prepack_w4_kernel<<<32, 256, 0, stream>>>(W4, Wpk);

    gcn_l1<<<2048, 256, 0, stream>>>(g0, meta, csr_src, dis, W1, b1, g1, N, 2048 * 4);

    const int ABLK = (N + 3) / 4;
    const int GBLK = (N + 63) / 64;

    agg_kernel<16><<<ABLK, 256, 0, stream>>>(g1, meta, csr_src, dis, aggb, N);
    gemm_kernel<16, 32, true><<<GBLK, 256, 0, stream>>>(aggb, W2, b2, dis, g2h, N);

    agg_half_kernel<32, false><<<ABLK, 256, 0, stream>>>(g2h, meta, csr_src, dis, aggb, N);
    gemm_kernel<32, 64, true><<<GBLK, 256, 0, stream>>>(aggb, W3, b3, dis, g3h, N);

    agg_half_kernel<64, true><<<ABLK, 256, 0, stream>>>(g3h, meta, csr_src, dis, aggh, N);
    gemm4_mfma_kernel<<<GBLK, 256, 0, stream>>>(aggh, Wpk, b4, batch, pooled, N);

    mlp_kernel<<<G, 64, 0, stream>>>(pooled, W5, b5, W6, b6, out);
}